// Round 1
// baseline (1071.357 us; speedup 1.0000x reference)
//
#include <hip/hip_runtime.h>
#include <hip/hip_bf16.h>

#define NNODES 100000
#define NEDGES 1600000

// ---------------- degree histogram ----------------
__global__ void deg_kernel(const int* __restrict__ dst, int* __restrict__ deg) {
    int e = blockIdx.x * blockDim.x + threadIdx.x;
    if (e < NEDGES) atomicAdd(&deg[dst[e]], 1);
}

// ---------------- 3-kernel exclusive scan over deg -> rowoff ----------------
// scan1: per-block (512 elems / block) local exclusive scan + block totals
__global__ void scan1_kernel(const int* __restrict__ deg, int* __restrict__ rowoff,
                             int* __restrict__ partial) {
    __shared__ int lds[256];
    int t = threadIdx.x;
    int base = blockIdx.x << 9;
    int i0 = base + 2 * t;
    int a = (i0 < NNODES) ? deg[i0] : 0;
    int b = (i0 + 1 < NNODES) ? deg[i0 + 1] : 0;
    int tsum = a + b;
    lds[t] = tsum;
    __syncthreads();
    // Hillis-Steele inclusive scan over 256 thread-sums
    for (int s = 1; s < 256; s <<= 1) {
        int v = (t >= s) ? lds[t - s] : 0;
        __syncthreads();
        lds[t] += v;
        __syncthreads();
    }
    int incl = lds[t];
    int excl = incl - tsum;
    if (i0 < NNODES) rowoff[i0] = excl;
    if (i0 + 1 < NNODES) rowoff[i0 + 1] = excl + a;
    if (t == 255) partial[blockIdx.x] = incl;  // block total
}

// scan2: exclusive scan of block totals (nb <= 256) in one block
__global__ void scan2_kernel(int* __restrict__ partial, int nb) {
    __shared__ int lds[256];
    int t = threadIdx.x;
    int v = (t < nb) ? partial[t] : 0;
    lds[t] = v;
    __syncthreads();
    for (int s = 1; s < 256; s <<= 1) {
        int u = (t >= s) ? lds[t - s] : 0;
        __syncthreads();
        lds[t] += u;
        __syncthreads();
    }
    if (t < nb) partial[t] = lds[t] - v;  // exclusive
}

// scan3: add block prefixes
__global__ void scan3_kernel(int* __restrict__ rowoff, const int* __restrict__ partial) {
    int i = blockIdx.x * blockDim.x + threadIdx.x;
    if (i < NNODES) rowoff[i] += partial[i >> 9];
}

// ---------------- dinv = deg>0 ? rsqrt(deg) : 0 ----------------
__global__ void dinv_kernel(const int* __restrict__ deg, float* __restrict__ dinv) {
    int i = blockIdx.x * blockDim.x + threadIdx.x;
    if (i < NNODES) {
        int d = deg[i];
        dinv[i] = (d > 0) ? rsqrtf((float)d) : 0.0f;
    }
}

// ---------------- CSR scatter (counting sort by dst) ----------------
__global__ void scatter_kernel(const int* __restrict__ dst, const int* __restrict__ src,
                               const int* __restrict__ rowoff, int* __restrict__ cursor,
                               int* __restrict__ col) {
    int e = blockIdx.x * blockDim.x + threadIdx.x;
    if (e < NEDGES) {
        int d = dst[e];
        int pos = rowoff[d] + atomicAdd(&cursor[d], 1);
        col[pos] = src[e];
    }
}

// ---------------- KProp step: hout = hin + dinv[i] * sum_e dinv[c]*hin[c] ----------------
// one wave per node, lane = feature
__global__ __launch_bounds__(256) void kprop_kernel(
    const float* __restrict__ hin, float* __restrict__ hout,
    const int* __restrict__ rowoff, const int* __restrict__ deg,
    const int* __restrict__ col, const float* __restrict__ dinv) {
    int node = blockIdx.x * 4 + (threadIdx.x >> 6);
    if (node >= NNODES) return;
    int lane = threadIdx.x & 63;
    int beg = rowoff[node];
    int end = beg + deg[node];
    float acc = 0.0f;
    for (int e = beg; e < end; ++e) {
        int c = col[e];
        acc += dinv[c] * hin[c * 64 + lane];
    }
    hout[node * 64 + lane] = hin[node * 64 + lane] + dinv[node] * acc;
}

// ---------------- SAGE1: agg = mean-neighbor; h' = selu(agg@W2l + h@W2r + b2) ----------------
__global__ __launch_bounds__(256) void sage1_kernel(
    const float* __restrict__ hin, float* __restrict__ hout,
    const int* __restrict__ rowoff, const int* __restrict__ deg,
    const int* __restrict__ col,
    const float* __restrict__ W2l, const float* __restrict__ W2r,
    const float* __restrict__ b2) {
    __shared__ float Wl[64 * 64];
    __shared__ float Wr[64 * 64];
    for (int i = threadIdx.x; i < 4096; i += 256) {
        Wl[i] = W2l[i];
        Wr[i] = W2r[i];
    }
    __syncthreads();
    int node = blockIdx.x * 4 + (threadIdx.x >> 6);
    if (node >= NNODES) return;
    int lane = threadIdx.x & 63;
    int beg = rowoff[node];
    int dg = deg[node];
    float aggsum = 0.0f;
    for (int e = beg; e < beg + dg; ++e) {
        int c = col[e];
        aggsum += hin[c * 64 + lane];
    }
    float agg = aggsum / (float)((dg > 0) ? dg : 1);
    float h = hin[node * 64 + lane];
    float acc = b2[lane];
#pragma unroll 8
    for (int k = 0; k < 64; ++k) {
        float ak = __shfl(agg, k);
        float hk = __shfl(h, k);
        acc += ak * Wl[k * 64 + lane] + hk * Wr[k * 64 + lane];
    }
    // SELU
    const float lam = 1.0507009873554804934193349852946f;
    const float alp = 1.6732632423543772848170429916717f;
    float o = (acc > 0.0f) ? lam * acc : lam * alp * expm1f(acc);
    hout[node * 64 + lane] = o;
}

// ---------------- SAGE2 + softmax(16) ----------------
__global__ __launch_bounds__(256) void sage2_kernel(
    const float* __restrict__ hin, float* __restrict__ out,
    const int* __restrict__ rowoff, const int* __restrict__ deg,
    const int* __restrict__ col,
    const float* __restrict__ W3l, const float* __restrict__ W3r,
    const float* __restrict__ b3) {
    __shared__ float Wl[64 * 16];
    __shared__ float Wr[64 * 16];
    for (int i = threadIdx.x; i < 1024; i += 256) {
        Wl[i] = W3l[i];
        Wr[i] = W3r[i];
    }
    __syncthreads();
    int node = blockIdx.x * 4 + (threadIdx.x >> 6);
    if (node >= NNODES) return;
    int lane = threadIdx.x & 63;
    int beg = rowoff[node];
    int dg = deg[node];
    float aggsum = 0.0f;
    for (int e = beg; e < beg + dg; ++e) {
        int c = col[e];
        aggsum += hin[c * 64 + lane];
    }
    float agg = aggsum / (float)((dg > 0) ? dg : 1);
    float h = hin[node * 64 + lane];
    // out[d] = b3[d] + sum_k agg[k]*W3l[k][d] + h[k]*W3r[k][d]
    // lane d = lane&15 handles k in [16*(lane>>4), +16), then reduce across 4 groups
    int d = lane & 15;
    int k0 = (lane >> 4) << 4;
    float acc = 0.0f;
#pragma unroll
    for (int kk = 0; kk < 16; ++kk) {
        int k = k0 + kk;
        float ak = __shfl(agg, k);
        float hk = __shfl(h, k);
        acc += ak * Wl[k * 16 + d] + hk * Wr[k * 16 + d];
    }
    acc += __shfl_xor(acc, 16);
    acc += __shfl_xor(acc, 32);
    acc += b3[d];
    // softmax over the 16 outputs (replicated 4x across the wave)
    float m = acc;
    m = fmaxf(m, __shfl_xor(m, 1));
    m = fmaxf(m, __shfl_xor(m, 2));
    m = fmaxf(m, __shfl_xor(m, 4));
    m = fmaxf(m, __shfl_xor(m, 8));
    float ex = expf(acc - m);
    float s = ex;
    s += __shfl_xor(s, 1);
    s += __shfl_xor(s, 2);
    s += __shfl_xor(s, 4);
    s += __shfl_xor(s, 8);
    float p = ex / s;
    if (lane < 16) out[node * 16 + lane] = p;
}

extern "C" void kernel_launch(void* const* d_in, const int* in_sizes, int n_in,
                              void* d_out, int out_size, void* d_ws, size_t ws_size,
                              hipStream_t stream) {
    const float* x   = (const float*)d_in[0];
    const int*   ei  = (const int*)d_in[1];
    const float* W2l = (const float*)d_in[2];
    const float* W2r = (const float*)d_in[3];
    const float* b2  = (const float*)d_in[4];
    const float* W3l = (const float*)d_in[5];
    const float* W3r = (const float*)d_in[6];
    const float* b3  = (const float*)d_in[7];
    float* out = (float*)d_out;

    const int* dst = ei;           // edge_index[0]
    const int* src = ei + NEDGES;  // edge_index[1]

    char* ws = (char*)d_ws;
    float* h0     = (float*)ws; ws += (size_t)NNODES * 64 * 4;
    float* h1     = (float*)ws; ws += (size_t)NNODES * 64 * 4;
    int*   col    = (int*)ws;   ws += (size_t)NEDGES * 4;
    int*   deg    = (int*)ws;   ws += (size_t)NNODES * 4;
    int*   rowoff = (int*)ws;   ws += (size_t)NNODES * 4;
    int*   cursor = (int*)ws;   ws += (size_t)NNODES * 4;
    float* dinv   = (float*)ws; ws += (size_t)NNODES * 4;
    int*   partial= (int*)ws;   ws += 256 * 4;

    hipMemsetAsync(deg, 0, (size_t)NNODES * 4, stream);
    hipMemsetAsync(cursor, 0, (size_t)NNODES * 4, stream);

    deg_kernel<<<(NEDGES + 255) / 256, 256, 0, stream>>>(dst, deg);

    int nb = (NNODES + 511) / 512;  // 196
    scan1_kernel<<<nb, 256, 0, stream>>>(deg, rowoff, partial);
    scan2_kernel<<<1, 256, 0, stream>>>(partial, nb);
    scan3_kernel<<<(NNODES + 255) / 256, 256, 0, stream>>>(rowoff, partial);
    dinv_kernel<<<(NNODES + 255) / 256, 256, 0, stream>>>(deg, dinv);
    scatter_kernel<<<(NEDGES + 255) / 256, 256, 0, stream>>>(dst, src, rowoff, cursor, col);

    int nblk = (NNODES + 3) / 4;
    kprop_kernel<<<nblk, 256, 0, stream>>>(x,  h0, rowoff, deg, col, dinv);
    kprop_kernel<<<nblk, 256, 0, stream>>>(h0, h1, rowoff, deg, col, dinv);
    sage1_kernel<<<nblk, 256, 0, stream>>>(h1, h0, rowoff, deg, col, W2l, W2r, b2);
    sage2_kernel<<<nblk, 256, 0, stream>>>(h0, out, rowoff, deg, col, W3l, W3r, b3);
}

// Round 2
// 599.095 us; speedup vs baseline: 1.7883x; 1.7883x over previous
//
#include <hip/hip_runtime.h>
#include <hip/hip_bf16.h>

#define NNODES 100000
#define NEDGES 1600000

// ---------------- degree histogram ----------------
__global__ void deg_kernel(const int* __restrict__ dst, int* __restrict__ deg) {
    int e = blockIdx.x * blockDim.x + threadIdx.x;
    if (e < NEDGES) atomicAdd(&deg[dst[e]], 1);
}

// ---------------- 3-kernel exclusive scan over deg -> rowoff ----------------
__global__ void scan1_kernel(const int* __restrict__ deg, int* __restrict__ rowoff,
                             int* __restrict__ partial) {
    __shared__ int lds[256];
    int t = threadIdx.x;
    int base = blockIdx.x << 9;
    int i0 = base + 2 * t;
    int a = (i0 < NNODES) ? deg[i0] : 0;
    int b = (i0 + 1 < NNODES) ? deg[i0 + 1] : 0;
    int tsum = a + b;
    lds[t] = tsum;
    __syncthreads();
    for (int s = 1; s < 256; s <<= 1) {
        int v = (t >= s) ? lds[t - s] : 0;
        __syncthreads();
        lds[t] += v;
        __syncthreads();
    }
    int incl = lds[t];
    int excl = incl - tsum;
    if (i0 < NNODES) rowoff[i0] = excl;
    if (i0 + 1 < NNODES) rowoff[i0 + 1] = excl + a;
    if (t == 255) partial[blockIdx.x] = incl;
}

__global__ void scan2_kernel(int* __restrict__ partial, int nb) {
    __shared__ int lds[256];
    int t = threadIdx.x;
    int v = (t < nb) ? partial[t] : 0;
    lds[t] = v;
    __syncthreads();
    for (int s = 1; s < 256; s <<= 1) {
        int u = (t >= s) ? lds[t - s] : 0;
        __syncthreads();
        lds[t] += u;
        __syncthreads();
    }
    if (t < nb) partial[t] = lds[t] - v;
}

__global__ void scan3_kernel(int* __restrict__ rowoff, const int* __restrict__ partial) {
    int i = blockIdx.x * blockDim.x + threadIdx.x;
    if (i < NNODES) rowoff[i] += partial[i >> 9];
}

// ---------------- dinv ----------------
__global__ void dinv_kernel(const int* __restrict__ deg, float* __restrict__ dinv) {
    int i = blockIdx.x * blockDim.x + threadIdx.x;
    if (i < NNODES) {
        int d = deg[i];
        dinv[i] = (d > 0) ? rsqrtf((float)d) : 0.0f;
    }
}

// ---------------- CSR scatter ----------------
__global__ void scatter_kernel(const int* __restrict__ dst, const int* __restrict__ src,
                               const int* __restrict__ rowoff, int* __restrict__ cursor,
                               int* __restrict__ col) {
    int e = blockIdx.x * blockDim.x + threadIdx.x;
    if (e < NEDGES) {
        int d = dst[e];
        int pos = rowoff[d] + atomicAdd(&cursor[d], 1);
        col[pos] = src[e];
    }
}

// ---------------- g0 = dinv[n] * x[n][:] (float4 per thread) ----------------
__global__ void g0_kernel(const float* __restrict__ x, const float* __restrict__ dinv,
                          float* __restrict__ g0) {
    int t = blockIdx.x * 256 + threadIdx.x;
    if (t < NNODES * 16) {
        int node = t >> 4;
        float4 v = ((const float4*)x)[t];
        float di = dinv[node];
        float4 r = {di * v.x, di * v.y, di * v.z, di * v.w};
        ((float4*)g0)[t] = r;
    }
}

// ---------------- gather: 4 nodes per wave, float4 per lane, unroll-2 ----------------
// MODE 0: kprop writing h' and g'=dinv*h'   MODE 1: kprop writing h' only
// MODE 2: mean aggregate (agg = sum/degm)
template <int MODE>
__global__ __launch_bounds__(256) void gather4_kernel(
    const float* __restrict__ vin,   // gathered array (g for kprop, h for agg)
    const float* __restrict__ hin,   // residual input (kprop only)
    float* __restrict__ out0,        // h' (kprop) / agg (MODE 2)
    float* __restrict__ out1,        // g' (MODE 0)
    const int* __restrict__ rowoff, const int* __restrict__ deg,
    const int* __restrict__ col, const float* __restrict__ dinv) {
    int node = blockIdx.x * 16 + (threadIdx.x >> 4);   // 6250*16 == 100000 exactly
    int sub = threadIdx.x & 15;
    int beg = rowoff[node];
    int dg = deg[node];
    int end = beg + dg;
    float4 a0 = {0.f, 0.f, 0.f, 0.f};
    float4 a1 = {0.f, 0.f, 0.f, 0.f};
    int e = beg;
    for (; e + 2 <= end; e += 2) {
        int c0 = col[e];
        int c1 = col[e + 1];
        const float4 v0 = *(const float4*)(vin + (size_t)c0 * 64 + sub * 4);
        const float4 v1 = *(const float4*)(vin + (size_t)c1 * 64 + sub * 4);
        a0.x += v0.x; a0.y += v0.y; a0.z += v0.z; a0.w += v0.w;
        a1.x += v1.x; a1.y += v1.y; a1.z += v1.z; a1.w += v1.w;
    }
    if (e < end) {
        int c0 = col[e];
        const float4 v0 = *(const float4*)(vin + (size_t)c0 * 64 + sub * 4);
        a0.x += v0.x; a0.y += v0.y; a0.z += v0.z; a0.w += v0.w;
    }
    float4 acc = {a0.x + a1.x, a0.y + a1.y, a0.z + a1.z, a0.w + a1.w};
    size_t off = (size_t)node * 64 + sub * 4;
    if (MODE <= 1) {
        float di = dinv[node];
        const float4 h = *(const float4*)(hin + off);
        float4 hn = {h.x + di * acc.x, h.y + di * acc.y,
                     h.z + di * acc.z, h.w + di * acc.w};
        *(float4*)(out0 + off) = hn;
        if (MODE == 0) {
            float4 gn = {di * hn.x, di * hn.y, di * hn.z, di * hn.w};
            *(float4*)(out1 + off) = gn;
        }
    } else {
        float r = 1.0f / (float)(dg > 0 ? dg : 1);
        float4 av = {acc.x * r, acc.y * r, acc.z * r, acc.w * r};
        *(float4*)(out0 + off) = av;
    }
}

// ---------------- dense1: h' = selu(agg@W2l + h@W2r + b2) ----------------
// wave per node (grid-stride); W columns in registers; row broadcast via LDS.
__global__ __launch_bounds__(256) void dense1_kernel(
    const float* __restrict__ agg, const float* __restrict__ h,
    float* __restrict__ hout,
    const float* __restrict__ W2l, const float* __restrict__ W2r,
    const float* __restrict__ b2) {
    int lane = threadIdx.x & 63;
    int wib = threadIdx.x >> 6;
    int gw = (blockIdx.x << 2) + wib;
    int nw = gridDim.x << 2;
    float wl[64], wr[64];
#pragma unroll
    for (int k = 0; k < 64; ++k) {
        wl[k] = W2l[k * 64 + lane];
        wr[k] = W2r[k * 64 + lane];
    }
    float bias = b2[lane];
    __shared__ float rb[4][2][64];
    for (int n = gw; n < NNODES; n += nw) {
        size_t off = (size_t)n * 64;
        rb[wib][0][lane] = agg[off + lane];
        rb[wib][1][lane] = h[off + lane];
        float acc = bias;
#pragma unroll
        for (int kq = 0; kq < 16; ++kq) {
            float4 av = *(const float4*)&rb[wib][0][kq * 4];
            float4 hv = *(const float4*)&rb[wib][1][kq * 4];
            acc += av.x * wl[4 * kq] + av.y * wl[4 * kq + 1] +
                   av.z * wl[4 * kq + 2] + av.w * wl[4 * kq + 3];
            acc += hv.x * wr[4 * kq] + hv.y * wr[4 * kq + 1] +
                   hv.z * wr[4 * kq + 2] + hv.w * wr[4 * kq + 3];
        }
        const float lam = 1.0507009873554804934193349852946f;
        const float alp = 1.6732632423543772848170429916717f;
        float o = (acc > 0.0f) ? lam * acc : lam * alp * expm1f(acc);
        hout[off + lane] = o;
    }
}

// ---------------- dense2 + softmax(16) ----------------
// wave per node; lane = (quarter q, output d); W3 columns in registers.
__global__ __launch_bounds__(256) void dense2_kernel(
    const float* __restrict__ agg, const float* __restrict__ h,
    float* __restrict__ out,
    const float* __restrict__ W3l, const float* __restrict__ W3r,
    const float* __restrict__ b3) {
    int lane = threadIdx.x & 63;
    int wib = threadIdx.x >> 6;
    int d = lane & 15;
    int q = lane >> 4;
    float wl[16], wr[16];
#pragma unroll
    for (int kk = 0; kk < 16; ++kk) {
        wl[kk] = W3l[(q * 16 + kk) * 16 + d];
        wr[kk] = W3r[(q * 16 + kk) * 16 + d];
    }
    float bias = b3[d];
    __shared__ float rb[4][2][64];
    int gw = (blockIdx.x << 2) + wib;
    int nw = gridDim.x << 2;
    for (int n = gw; n < NNODES; n += nw) {
        size_t off = (size_t)n * 64;
        rb[wib][0][lane] = agg[off + lane];
        rb[wib][1][lane] = h[off + lane];
        float acc = 0.0f;
#pragma unroll
        for (int k4 = 0; k4 < 4; ++k4) {
            float4 av = *(const float4*)&rb[wib][0][q * 16 + k4 * 4];
            float4 hv = *(const float4*)&rb[wib][1][q * 16 + k4 * 4];
            acc += av.x * wl[4 * k4] + av.y * wl[4 * k4 + 1] +
                   av.z * wl[4 * k4 + 2] + av.w * wl[4 * k4 + 3];
            acc += hv.x * wr[4 * k4] + hv.y * wr[4 * k4 + 1] +
                   hv.z * wr[4 * k4 + 2] + hv.w * wr[4 * k4 + 3];
        }
        acc += __shfl_xor(acc, 16);
        acc += __shfl_xor(acc, 32);
        acc += bias;
        float m = acc;
        m = fmaxf(m, __shfl_xor(m, 1));
        m = fmaxf(m, __shfl_xor(m, 2));
        m = fmaxf(m, __shfl_xor(m, 4));
        m = fmaxf(m, __shfl_xor(m, 8));
        float ex = expf(acc - m);
        float s = ex;
        s += __shfl_xor(s, 1);
        s += __shfl_xor(s, 2);
        s += __shfl_xor(s, 4);
        s += __shfl_xor(s, 8);
        if (lane < 16) out[(size_t)n * 16 + lane] = ex / s;
    }
}

extern "C" void kernel_launch(void* const* d_in, const int* in_sizes, int n_in,
                              void* d_out, int out_size, void* d_ws, size_t ws_size,
                              hipStream_t stream) {
    const float* x   = (const float*)d_in[0];
    const int*   ei  = (const int*)d_in[1];
    const float* W2l = (const float*)d_in[2];
    const float* W2r = (const float*)d_in[3];
    const float* b2  = (const float*)d_in[4];
    const float* W3l = (const float*)d_in[5];
    const float* W3r = (const float*)d_in[6];
    const float* b3  = (const float*)d_in[7];
    float* out = (float*)d_out;

    const int* dst = ei;           // edge_index[0]
    const int* src = ei + NEDGES;  // edge_index[1]

    char* ws = (char*)d_ws;
    float* bufA   = (float*)ws; ws += (size_t)NNODES * 64 * 4;  // g0 -> h2
    float* bufB   = (float*)ws; ws += (size_t)NNODES * 64 * 4;  // h1 -> h3
    float* bufC   = (float*)ws; ws += (size_t)NNODES * 64 * 4;  // g1 -> agg
    int*   col    = (int*)ws;   ws += (size_t)NEDGES * 4;
    int*   deg    = (int*)ws;   ws += (size_t)NNODES * 4;
    int*   rowoff = (int*)ws;   ws += (size_t)NNODES * 4;
    int*   cursor = (int*)ws;   ws += (size_t)NNODES * 4;
    float* dinv   = (float*)ws; ws += (size_t)NNODES * 4;
    int*   partial= (int*)ws;   ws += 256 * 4;

    hipMemsetAsync(deg, 0, (size_t)NNODES * 4, stream);
    hipMemsetAsync(cursor, 0, (size_t)NNODES * 4, stream);

    deg_kernel<<<(NEDGES + 255) / 256, 256, 0, stream>>>(dst, deg);

    int nb = (NNODES + 511) / 512;  // 196
    scan1_kernel<<<nb, 256, 0, stream>>>(deg, rowoff, partial);
    scan2_kernel<<<1, 256, 0, stream>>>(partial, nb);
    scan3_kernel<<<(NNODES + 255) / 256, 256, 0, stream>>>(rowoff, partial);
    dinv_kernel<<<(NNODES + 255) / 256, 256, 0, stream>>>(deg, dinv);
    scatter_kernel<<<(NEDGES + 255) / 256, 256, 0, stream>>>(dst, src, rowoff, cursor, col);

    // g0 = dinv * x
    g0_kernel<<<(NNODES * 16 + 255) / 256, 256, 0, stream>>>(x, dinv, bufA);

    int ngather = NNODES / 16;  // 6250, exact
    // KProp step 1: h1 = x + dinv*sum(g0), g1 = dinv*h1
    gather4_kernel<0><<<ngather, 256, 0, stream>>>(bufA, x, bufB, bufC, rowoff, deg, col, dinv);
    // KProp step 2: h2 = h1 + dinv*sum(g1)
    gather4_kernel<1><<<ngather, 256, 0, stream>>>(bufC, bufB, bufA, nullptr, rowoff, deg, col, dinv);
    // SAGE1 aggregate: agg = mean(h2[neigh])
    gather4_kernel<2><<<ngather, 256, 0, stream>>>(bufA, nullptr, bufC, nullptr, rowoff, deg, col, dinv);
    // dense1: h3 = selu(agg@W2l + h2@W2r + b2)
    dense1_kernel<<<2048, 256, 0, stream>>>(bufC, bufA, bufB, W2l, W2r, b2);
    // SAGE2 aggregate: agg = mean(h3[neigh])
    gather4_kernel<2><<<ngather, 256, 0, stream>>>(bufB, nullptr, bufC, nullptr, rowoff, deg, col, dinv);
    // dense2 + softmax
    dense2_kernel<<<2048, 256, 0, stream>>>(bufC, bufB, out, W3l, W3r, b3);
}

// Round 3
// 467.216 us; speedup vs baseline: 2.2931x; 1.2823x over previous
//
#include <hip/hip_runtime.h>
#include <hip/hip_bf16.h>

#define NNODES 100000
#define NEDGES 1600000
#define NBUCK 196           // ceil(100000/512) buckets of 512 nodes
#define BCAP 13000          // slack capacity per bucket (mean 8192, sigma ~90)
#define SPLIT_TILE 2048
#define NSPLIT ((NEDGES + SPLIT_TILE - 1) / SPLIT_TILE)  // 782

__device__ __forceinline__ void f4add(float4& a, const float4& v) {
    a.x += v.x; a.y += v.y; a.z += v.z; a.w += v.w;
}

// ---------------- split: bucket edges by dst>>9 into slack regions ----------------
// packed u32 = (src << 9) | (dst & 511)
__global__ __launch_bounds__(256) void split_kernel(
    const int* __restrict__ dst, const int* __restrict__ src,
    int* __restrict__ gcur, unsigned* __restrict__ pairtmp) {
    __shared__ int lhist[NBUCK];
    __shared__ int lstart[NBUCK];
    __shared__ int ldst[SPLIT_TILE];
    int t = threadIdx.x;
    for (int i = t; i < NBUCK; i += 256) lhist[i] = 0;
    __syncthreads();
    int base = blockIdx.x * SPLIT_TILE;
    int n = min(SPLIT_TILE, NEDGES - base);
    for (int i = t; i < n; i += 256) {
        int d = dst[base + i];
        ldst[i] = d;
        atomicAdd(&lhist[d >> 9], 1);
    }
    __syncthreads();
    for (int i = t; i < NBUCK; i += 256) {
        int c = lhist[i];
        lstart[i] = (c > 0) ? atomicAdd(&gcur[i], c) : 0;
        lhist[i] = 0;  // reuse as local cursor
    }
    __syncthreads();
    for (int i = t; i < n; i += 256) {
        int d = ldst[i];
        int k = d >> 9;
        int s = src[base + i];
        int pos = lstart[k] + atomicAdd(&lhist[k], 1);
        pairtmp[(size_t)k * BCAP + pos] = ((unsigned)s << 9) | (unsigned)(d & 511);
    }
}

// ---------------- exclusive scan of 196 bucket counts ----------------
__global__ void bucketscan_kernel(const int* __restrict__ gcur, int* __restrict__ basearr) {
    __shared__ int lds[256];
    int t = threadIdx.x;
    int v = (t < NBUCK) ? gcur[t] : 0;
    lds[t] = v;
    __syncthreads();
    for (int s = 1; s < 256; s <<= 1) {
        int u = (t >= s) ? lds[t - s] : 0;
        __syncthreads();
        lds[t] += u;
        __syncthreads();
    }
    if (t < NBUCK) basearr[t] = lds[t] - v;
}

// ---------------- finalize: per-bucket CSR build + deg/rowoff/dinv + g0 ----------------
__global__ __launch_bounds__(256) void finalize_kernel(
    const unsigned* __restrict__ pairtmp, const int* __restrict__ gcur,
    const int* __restrict__ basearr, const float* __restrict__ x,
    int* __restrict__ col, int* __restrict__ deg, int* __restrict__ rowoff,
    float* __restrict__ dinv, float* __restrict__ g0) {
    __shared__ int ldeg[512];
    __shared__ int lcur[512];
    __shared__ float ldi[512];
    __shared__ int lsc[256];
    int k = blockIdx.x;
    int t = threadIdx.x;
    int node0 = k << 9;
    int ncount = min(512, NNODES - node0);
    int base = basearr[k];
    int count = gcur[k];
    ldeg[t] = 0;
    ldeg[t + 256] = 0;
    __syncthreads();
    const unsigned* pb = pairtmp + (size_t)k * BCAP;
    for (int i = t; i < count; i += 256) {
        atomicAdd(&ldeg[pb[i] & 511], 1);
    }
    __syncthreads();
    // 512-element exclusive scan (2 elems/thread + Hillis-Steele)
    int a = ldeg[2 * t], b = ldeg[2 * t + 1];
    int ts = a + b;
    lsc[t] = ts;
    __syncthreads();
    for (int s = 1; s < 256; s <<= 1) {
        int v = (t >= s) ? lsc[t - s] : 0;
        __syncthreads();
        lsc[t] += v;
        __syncthreads();
    }
    int excl = lsc[t] - ts;
    lcur[2 * t] = base + excl;
    lcur[2 * t + 1] = base + excl + a;
    if (2 * t < ncount) {
        int n0 = node0 + 2 * t;
        rowoff[n0] = base + excl;
        deg[n0] = a;
        float di = (a > 0) ? rsqrtf((float)a) : 0.0f;
        ldi[2 * t] = di;
        dinv[n0] = di;
    }
    if (2 * t + 1 < ncount) {
        int n1 = node0 + 2 * t + 1;
        rowoff[n1] = base + excl + a;
        deg[n1] = b;
        float di = (b > 0) ? rsqrtf((float)b) : 0.0f;
        ldi[2 * t + 1] = di;
        dinv[n1] = di;
    }
    __syncthreads();
    // scatter col within this bucket's contiguous region (L2-local)
    for (int i = t; i < count; i += 256) {
        unsigned p = pb[i];
        int dl = (int)(p & 511u);
        int s = (int)(p >> 9);
        int pos = atomicAdd(&lcur[dl], 1);
        col[pos] = s;
    }
    // fused g0 = dinv * x for this bucket's nodes
    const float4* x4 = (const float4*)x;
    float4* g4 = (float4*)g0;
    int f4count = ncount * 16;
    int b4 = node0 * 16;
    for (int j = t; j < f4count; j += 256) {
        float di = ldi[j >> 4];
        float4 v = x4[b4 + j];
        g4[b4 + j] = make_float4(di * v.x, di * v.y, di * v.z, di * v.w);
    }
}

// ---------------- gather: one node per 64-lane wave ----------------
// 4 groups x 16 lanes x float4; unroll-2 -> 8 rows in flight; no cross-node divergence
// MODE 0: h' = h + dinv*sum, g' = dinv*h'   MODE 1: h' only   MODE 2: mean aggregate
template <int MODE>
__global__ __launch_bounds__(256) void gatherw_kernel(
    const float* __restrict__ vin, const float* __restrict__ hin,
    float* __restrict__ out0, float* __restrict__ out1,
    const int* __restrict__ rowoff, const int* __restrict__ deg,
    const int* __restrict__ col, const float* __restrict__ dinv) {
    int node = blockIdx.x * 4 + (threadIdx.x >> 6);  // 25000*4 == 100000 exactly
    int lane = threadIdx.x & 63;
    int sub = lane & 15;
    int g = lane >> 4;
    int beg = rowoff[node];
    int dg = deg[node];
    int end = beg + dg;
    float4 a0 = {0.f, 0.f, 0.f, 0.f};
    float4 a1 = {0.f, 0.f, 0.f, 0.f};
    int e = beg + g;
    for (; e + 4 < end; e += 8) {
        int c0 = col[e];
        int c1 = col[e + 4];
        float4 v0 = *(const float4*)(vin + (size_t)c0 * 64 + sub * 4);
        float4 v1 = *(const float4*)(vin + (size_t)c1 * 64 + sub * 4);
        f4add(a0, v0);
        f4add(a1, v1);
    }
    if (e < end) {
        int c0 = col[e];
        float4 v0 = *(const float4*)(vin + (size_t)c0 * 64 + sub * 4);
        f4add(a0, v0);
    }
    f4add(a0, a1);
    // reduce across the 4 groups
    a0.x += __shfl_xor(a0.x, 16); a0.y += __shfl_xor(a0.y, 16);
    a0.z += __shfl_xor(a0.z, 16); a0.w += __shfl_xor(a0.w, 16);
    a0.x += __shfl_xor(a0.x, 32); a0.y += __shfl_xor(a0.y, 32);
    a0.z += __shfl_xor(a0.z, 32); a0.w += __shfl_xor(a0.w, 32);
    if (lane < 16) {
        size_t off = (size_t)node * 64 + sub * 4;
        if (MODE <= 1) {
            float di = dinv[node];
            float4 h = *(const float4*)(hin + off);
            float4 hn = make_float4(h.x + di * a0.x, h.y + di * a0.y,
                                    h.z + di * a0.z, h.w + di * a0.w);
            *(float4*)(out0 + off) = hn;
            if (MODE == 0) {
                *(float4*)(out1 + off) =
                    make_float4(di * hn.x, di * hn.y, di * hn.z, di * hn.w);
            }
        } else {
            float r = 1.0f / (float)(dg > 0 ? dg : 1);
            *(float4*)(out0 + off) = make_float4(a0.x * r, a0.y * r, a0.z * r, a0.w * r);
        }
    }
}

// ---------------- dense1: h' = selu(agg@W2l + h@W2r + b2) ----------------
__global__ __launch_bounds__(256) void dense1_kernel(
    const float* __restrict__ agg, const float* __restrict__ h,
    float* __restrict__ hout,
    const float* __restrict__ W2l, const float* __restrict__ W2r,
    const float* __restrict__ b2) {
    int lane = threadIdx.x & 63;
    int wib = threadIdx.x >> 6;
    int gw = (blockIdx.x << 2) + wib;
    int nw = gridDim.x << 2;
    float wl[64], wr[64];
#pragma unroll
    for (int k = 0; k < 64; ++k) {
        wl[k] = W2l[k * 64 + lane];
        wr[k] = W2r[k * 64 + lane];
    }
    float bias = b2[lane];
    __shared__ float rb[4][2][64];
    for (int n = gw; n < NNODES; n += nw) {
        size_t off = (size_t)n * 64;
        rb[wib][0][lane] = agg[off + lane];
        rb[wib][1][lane] = h[off + lane];
        float acc = bias;
#pragma unroll
        for (int kq = 0; kq < 16; ++kq) {
            float4 av = *(const float4*)&rb[wib][0][kq * 4];
            float4 hv = *(const float4*)&rb[wib][1][kq * 4];
            acc += av.x * wl[4 * kq] + av.y * wl[4 * kq + 1] +
                   av.z * wl[4 * kq + 2] + av.w * wl[4 * kq + 3];
            acc += hv.x * wr[4 * kq] + hv.y * wr[4 * kq + 1] +
                   hv.z * wr[4 * kq + 2] + hv.w * wr[4 * kq + 3];
        }
        const float lam = 1.0507009873554804934193349852946f;
        const float alp = 1.6732632423543772848170429916717f;
        float o = (acc > 0.0f) ? lam * acc : lam * alp * expm1f(acc);
        hout[off + lane] = o;
    }
}

// ---------------- dense2 + softmax(16) ----------------
__global__ __launch_bounds__(256) void dense2_kernel(
    const float* __restrict__ agg, const float* __restrict__ h,
    float* __restrict__ out,
    const float* __restrict__ W3l, const float* __restrict__ W3r,
    const float* __restrict__ b3) {
    int lane = threadIdx.x & 63;
    int wib = threadIdx.x >> 6;
    int d = lane & 15;
    int q = lane >> 4;
    float wl[16], wr[16];
#pragma unroll
    for (int kk = 0; kk < 16; ++kk) {
        wl[kk] = W3l[(q * 16 + kk) * 16 + d];
        wr[kk] = W3r[(q * 16 + kk) * 16 + d];
    }
    float bias = b3[d];
    __shared__ float rb[4][2][64];
    int gw = (blockIdx.x << 2) + wib;
    int nw = gridDim.x << 2;
    for (int n = gw; n < NNODES; n += nw) {
        size_t off = (size_t)n * 64;
        rb[wib][0][lane] = agg[off + lane];
        rb[wib][1][lane] = h[off + lane];
        float acc = 0.0f;
#pragma unroll
        for (int k4 = 0; k4 < 4; ++k4) {
            float4 av = *(const float4*)&rb[wib][0][q * 16 + k4 * 4];
            float4 hv = *(const float4*)&rb[wib][1][q * 16 + k4 * 4];
            acc += av.x * wl[4 * k4] + av.y * wl[4 * k4 + 1] +
                   av.z * wl[4 * k4 + 2] + av.w * wl[4 * k4 + 3];
            acc += hv.x * wr[4 * k4] + hv.y * wr[4 * k4 + 1] +
                   hv.z * wr[4 * k4 + 2] + hv.w * wr[4 * k4 + 3];
        }
        acc += __shfl_xor(acc, 16);
        acc += __shfl_xor(acc, 32);
        acc += bias;
        float m = acc;
        m = fmaxf(m, __shfl_xor(m, 1));
        m = fmaxf(m, __shfl_xor(m, 2));
        m = fmaxf(m, __shfl_xor(m, 4));
        m = fmaxf(m, __shfl_xor(m, 8));
        float ex = expf(acc - m);
        float s = ex;
        s += __shfl_xor(s, 1);
        s += __shfl_xor(s, 2);
        s += __shfl_xor(s, 4);
        s += __shfl_xor(s, 8);
        if (lane < 16) out[(size_t)n * 16 + lane] = ex / s;
    }
}

extern "C" void kernel_launch(void* const* d_in, const int* in_sizes, int n_in,
                              void* d_out, int out_size, void* d_ws, size_t ws_size,
                              hipStream_t stream) {
    const float* x   = (const float*)d_in[0];
    const int*   ei  = (const int*)d_in[1];
    const float* W2l = (const float*)d_in[2];
    const float* W2r = (const float*)d_in[3];
    const float* b2  = (const float*)d_in[4];
    const float* W3l = (const float*)d_in[5];
    const float* W3r = (const float*)d_in[6];
    const float* b3  = (const float*)d_in[7];
    float* out = (float*)d_out;

    const int* dst = ei;           // edge_index[0]
    const int* src = ei + NEDGES;  // edge_index[1]

    char* ws = (char*)d_ws;
    float*    bufA    = (float*)ws;    ws += (size_t)NNODES * 64 * 4;  // g0 -> h2
    float*    bufB    = (float*)ws;    ws += (size_t)NNODES * 64 * 4;  // h1 -> h3
    float*    bufC    = (float*)ws;    ws += (size_t)NNODES * 64 * 4;  // g1 -> agg
    int*      col     = (int*)ws;      ws += (size_t)NEDGES * 4;
    unsigned* pairtmp = (unsigned*)ws; ws += (size_t)NBUCK * BCAP * 4;
    int*      deg     = (int*)ws;      ws += (size_t)NNODES * 4;
    int*      rowoff  = (int*)ws;      ws += (size_t)NNODES * 4;
    float*    dinv    = (float*)ws;    ws += (size_t)NNODES * 4;
    int*      gcur    = (int*)ws;      ws += NBUCK * 4;
    int*      basearr = (int*)ws;      ws += NBUCK * 4;

    hipMemsetAsync(gcur, 0, NBUCK * 4, stream);

    split_kernel<<<NSPLIT, 256, 0, stream>>>(dst, src, gcur, pairtmp);
    bucketscan_kernel<<<1, 256, 0, stream>>>(gcur, basearr);
    finalize_kernel<<<NBUCK, 256, 0, stream>>>(pairtmp, gcur, basearr, x,
                                               col, deg, rowoff, dinv, bufA);

    int nblk = NNODES / 4;  // 25000, exact
    // KProp step 1: h1 = x + dinv*sum(g0), g1 = dinv*h1
    gatherw_kernel<0><<<nblk, 256, 0, stream>>>(bufA, x, bufB, bufC, rowoff, deg, col, dinv);
    // KProp step 2: h2 = h1 + dinv*sum(g1)
    gatherw_kernel<1><<<nblk, 256, 0, stream>>>(bufC, bufB, bufA, nullptr, rowoff, deg, col, dinv);
    // SAGE1 aggregate: agg = mean(h2[neigh])
    gatherw_kernel<2><<<nblk, 256, 0, stream>>>(bufA, nullptr, bufC, nullptr, rowoff, deg, col, dinv);
    // dense1: h3 = selu(agg@W2l + h2@W2r + b2)
    dense1_kernel<<<2048, 256, 0, stream>>>(bufC, bufA, bufB, W2l, W2r, b2);
    // SAGE2 aggregate: agg = mean(h3[neigh])
    gatherw_kernel<2><<<nblk, 256, 0, stream>>>(bufB, nullptr, bufC, nullptr, rowoff, deg, col, dinv);
    // dense2 + softmax
    dense2_kernel<<<2048, 256, 0, stream>>>(bufC, bufB, out, W3l, W3r, b3);
}

// Round 4
// 412.550 us; speedup vs baseline: 2.5969x; 1.1325x over previous
//
#include <hip/hip_runtime.h>
#include <hip/hip_bf16.h>

#define NNODES 100000
#define NEDGES 1600000
#define NBUCK 391           // ceil(100000/256) buckets of 256 nodes
#define BCAP 4800           // slack capacity per bucket (mean 4096, sigma ~64)
#define SPLIT_TILE 2048
#define NSPLIT ((NEDGES + SPLIT_TILE - 1) / SPLIT_TILE)  // 782

__device__ __forceinline__ void f4add(float4& a, const float4& v) {
    a.x += v.x; a.y += v.y; a.z += v.z; a.w += v.w;
}

// bf16 (stored as ushort) -> f32 : exact, one shift
__device__ __forceinline__ float4 b4tof4(ushort4 u) {
    return make_float4(__uint_as_float((unsigned)u.x << 16),
                       __uint_as_float((unsigned)u.y << 16),
                       __uint_as_float((unsigned)u.z << 16),
                       __uint_as_float((unsigned)u.w << 16));
}

// f32 -> bf16 RNE
__device__ __forceinline__ unsigned short f2b(float f) {
    unsigned u = __float_as_uint(f);
    u += 0x7fffu + ((u >> 16) & 1u);
    return (unsigned short)(u >> 16);
}

// ---------------- split: bucket edges by dst>>8 into slack regions ----------------
// packed u32 = (src << 8) | (dst & 255)   (src < 2^17)
__global__ __launch_bounds__(256) void split_kernel(
    const int* __restrict__ dst, const int* __restrict__ src,
    int* __restrict__ gcur, unsigned* __restrict__ pairtmp) {
    __shared__ int lhist[NBUCK];
    __shared__ int lstart[NBUCK];
    __shared__ int ldst[SPLIT_TILE];
    int t = threadIdx.x;
    for (int i = t; i < NBUCK; i += 256) lhist[i] = 0;
    __syncthreads();
    int base = blockIdx.x * SPLIT_TILE;
    int n = min(SPLIT_TILE, NEDGES - base);
    for (int i = t; i < n; i += 256) {
        int d = dst[base + i];
        ldst[i] = d;
        atomicAdd(&lhist[d >> 8], 1);
    }
    __syncthreads();
    for (int i = t; i < NBUCK; i += 256) {
        int c = lhist[i];
        lstart[i] = (c > 0) ? atomicAdd(&gcur[i], c) : 0;
        lhist[i] = 0;  // reuse as local cursor
    }
    __syncthreads();
    for (int i = t; i < n; i += 256) {
        int d = ldst[i];
        int k = d >> 8;
        int s = src[base + i];
        int pos = lstart[k] + atomicAdd(&lhist[k], 1);
        pairtmp[(size_t)k * BCAP + pos] = ((unsigned)s << 8) | (unsigned)(d & 255);
    }
}

// ---------------- exclusive scan of 391 bucket counts ----------------
__global__ void bucketscan_kernel(const int* __restrict__ gcur, int* __restrict__ basearr) {
    __shared__ int lds[512];
    int t = threadIdx.x;
    int v = (t < NBUCK) ? gcur[t] : 0;
    lds[t] = v;
    __syncthreads();
    for (int s = 1; s < 512; s <<= 1) {
        int u = (t >= s) ? lds[t - s] : 0;
        __syncthreads();
        lds[t] += u;
        __syncthreads();
    }
    if (t < NBUCK) basearr[t] = lds[t] - v;
}

// ---------------- finalize: per-bucket CSR build + deg/rowoff/dinv + g0b ----------------
__global__ __launch_bounds__(256) void finalize_kernel(
    const unsigned* __restrict__ pairtmp, const int* __restrict__ gcur,
    const int* __restrict__ basearr, const float* __restrict__ x,
    int* __restrict__ col, int* __restrict__ deg, int* __restrict__ rowoff,
    float* __restrict__ dinv, unsigned short* __restrict__ g0b) {
    __shared__ int ldeg[256];
    __shared__ int lcur[256];
    __shared__ float ldi[256];
    __shared__ int lsc[256];
    int k = blockIdx.x;
    int t = threadIdx.x;
    int node0 = k << 8;
    int ncount = min(256, NNODES - node0);
    int base = basearr[k];
    int count = gcur[k];
    ldeg[t] = 0;
    __syncthreads();
    const unsigned* pb = pairtmp + (size_t)k * BCAP;
    for (int i = t; i < count; i += 256) {
        atomicAdd(&ldeg[pb[i] & 255], 1);
    }
    __syncthreads();
    int a = ldeg[t];
    lsc[t] = a;
    __syncthreads();
    for (int s = 1; s < 256; s <<= 1) {
        int v = (t >= s) ? lsc[t - s] : 0;
        __syncthreads();
        lsc[t] += v;
        __syncthreads();
    }
    int excl = lsc[t] - a;
    lcur[t] = base + excl;
    if (t < ncount) {
        int n0 = node0 + t;
        rowoff[n0] = base + excl;
        deg[n0] = a;
        float di = (a > 0) ? rsqrtf((float)a) : 0.0f;
        ldi[t] = di;
        dinv[n0] = di;
    }
    __syncthreads();
    // scatter col within this bucket's contiguous region (L2-local)
    for (int i = t; i < count; i += 256) {
        unsigned p = pb[i];
        int dl = (int)(p & 255u);
        int s = (int)(p >> 8);
        int pos = atomicAdd(&lcur[dl], 1);
        col[pos] = s;
    }
    // fused g0b = bf16(dinv * x) for this bucket's nodes
    const float4* x4 = (const float4*)x;
    int f4count = ncount * 16;
    int b4 = node0 * 16;
    for (int j = t; j < f4count; j += 256) {
        float di = ldi[j >> 4];
        float4 v = x4[b4 + j];
        ushort4 u;
        u.x = f2b(di * v.x); u.y = f2b(di * v.y);
        u.z = f2b(di * v.z); u.w = f2b(di * v.w);
        *(ushort4*)(g0b + (size_t)(b4 + j) * 4) = u;
    }
}

// ---------------- gather: one node per 64-lane wave, bf16 rows ----------------
// 4 groups x 16 lanes x ushort4(8B); unroll-2 -> 8 rows in flight
// MODE 0: h' = h + dinv*sum; outb = bf16(dinv*h')   (KProp step w/ next-g)
// MODE 1: h' = h + dinv*sum; outb = bf16(h')        (KProp step w/ h-copy)
// MODE 2: mean aggregate (fp32 out only)
template <int MODE>
__global__ __launch_bounds__(256) void gatherw_kernel(
    const unsigned short* __restrict__ vin, const float* __restrict__ hin,
    float* __restrict__ outf, unsigned short* __restrict__ outb,
    const int* __restrict__ rowoff, const int* __restrict__ deg,
    const int* __restrict__ col, const float* __restrict__ dinv) {
    int node = blockIdx.x * 4 + (threadIdx.x >> 6);  // 25000*4 == 100000 exactly
    int lane = threadIdx.x & 63;
    int sub = lane & 15;
    int g = lane >> 4;
    int beg = rowoff[node];
    int dg = deg[node];
    int end = beg + dg;
    float4 a0 = {0.f, 0.f, 0.f, 0.f};
    float4 a1 = {0.f, 0.f, 0.f, 0.f};
    int e = beg + g;
    for (; e + 4 < end; e += 8) {
        int c0 = col[e];
        int c1 = col[e + 4];
        ushort4 u0 = *(const ushort4*)(vin + (size_t)c0 * 64 + sub * 4);
        ushort4 u1 = *(const ushort4*)(vin + (size_t)c1 * 64 + sub * 4);
        f4add(a0, b4tof4(u0));
        f4add(a1, b4tof4(u1));
    }
    if (e < end) {
        int c0 = col[e];
        ushort4 u0 = *(const ushort4*)(vin + (size_t)c0 * 64 + sub * 4);
        f4add(a0, b4tof4(u0));
    }
    f4add(a0, a1);
    a0.x += __shfl_xor(a0.x, 16); a0.y += __shfl_xor(a0.y, 16);
    a0.z += __shfl_xor(a0.z, 16); a0.w += __shfl_xor(a0.w, 16);
    a0.x += __shfl_xor(a0.x, 32); a0.y += __shfl_xor(a0.y, 32);
    a0.z += __shfl_xor(a0.z, 32); a0.w += __shfl_xor(a0.w, 32);
    if (lane < 16) {
        size_t off = (size_t)node * 64 + sub * 4;
        if (MODE <= 1) {
            float di = dinv[node];
            float4 h = *(const float4*)(hin + off);
            float4 hn = make_float4(h.x + di * a0.x, h.y + di * a0.y,
                                    h.z + di * a0.z, h.w + di * a0.w);
            *(float4*)(outf + off) = hn;
            float s = (MODE == 0) ? di : 1.0f;
            ushort4 u;
            u.x = f2b(s * hn.x); u.y = f2b(s * hn.y);
            u.z = f2b(s * hn.z); u.w = f2b(s * hn.w);
            *(ushort4*)(outb + off) = u;
        } else {
            float r = 1.0f / (float)(dg > 0 ? dg : 1);
            *(float4*)(outf + off) = make_float4(a0.x * r, a0.y * r, a0.z * r, a0.w * r);
        }
    }
}

// ---------------- dense1: h' = selu(agg@W2l + h@W2r + b2); also bf16 copy ----------------
__global__ __launch_bounds__(256) void dense1_kernel(
    const float* __restrict__ agg, const float* __restrict__ h,
    float* __restrict__ houtf, unsigned short* __restrict__ houtb,
    const float* __restrict__ W2l, const float* __restrict__ W2r,
    const float* __restrict__ b2) {
    int lane = threadIdx.x & 63;
    int wib = threadIdx.x >> 6;
    int gw = (blockIdx.x << 2) + wib;
    int nw = gridDim.x << 2;
    float wl[64], wr[64];
#pragma unroll
    for (int k = 0; k < 64; ++k) {
        wl[k] = W2l[k * 64 + lane];
        wr[k] = W2r[k * 64 + lane];
    }
    float bias = b2[lane];
    __shared__ float rb[4][2][64];
    for (int n = gw; n < NNODES; n += nw) {
        size_t off = (size_t)n * 64;
        rb[wib][0][lane] = agg[off + lane];
        rb[wib][1][lane] = h[off + lane];
        float acc = bias;
#pragma unroll
        for (int kq = 0; kq < 16; ++kq) {
            float4 av = *(const float4*)&rb[wib][0][kq * 4];
            float4 hv = *(const float4*)&rb[wib][1][kq * 4];
            acc += av.x * wl[4 * kq] + av.y * wl[4 * kq + 1] +
                   av.z * wl[4 * kq + 2] + av.w * wl[4 * kq + 3];
            acc += hv.x * wr[4 * kq] + hv.y * wr[4 * kq + 1] +
                   hv.z * wr[4 * kq + 2] + hv.w * wr[4 * kq + 3];
        }
        const float lam = 1.0507009873554804934193349852946f;
        const float alp = 1.6732632423543772848170429916717f;
        float o = (acc > 0.0f) ? lam * acc : lam * alp * expm1f(acc);
        houtf[off + lane] = o;
        float oo = __shfl_xor(o, 1);
        if (!(lane & 1)) {
            ushort2 p;
            p.x = f2b(o); p.y = f2b(oo);
            *(ushort2*)(houtb + off + lane) = p;
        }
    }
}

// ---------------- dense2 + softmax(16) ----------------
__global__ __launch_bounds__(256) void dense2_kernel(
    const float* __restrict__ agg, const float* __restrict__ h,
    float* __restrict__ out,
    const float* __restrict__ W3l, const float* __restrict__ W3r,
    const float* __restrict__ b3) {
    int lane = threadIdx.x & 63;
    int wib = threadIdx.x >> 6;
    int d = lane & 15;
    int q = lane >> 4;
    float wl[16], wr[16];
#pragma unroll
    for (int kk = 0; kk < 16; ++kk) {
        wl[kk] = W3l[(q * 16 + kk) * 16 + d];
        wr[kk] = W3r[(q * 16 + kk) * 16 + d];
    }
    float bias = b3[d];
    __shared__ float rb[4][2][64];
    int gw = (blockIdx.x << 2) + wib;
    int nw = gridDim.x << 2;
    for (int n = gw; n < NNODES; n += nw) {
        size_t off = (size_t)n * 64;
        rb[wib][0][lane] = agg[off + lane];
        rb[wib][1][lane] = h[off + lane];
        float acc = 0.0f;
#pragma unroll
        for (int k4 = 0; k4 < 4; ++k4) {
            float4 av = *(const float4*)&rb[wib][0][q * 16 + k4 * 4];
            float4 hv = *(const float4*)&rb[wib][1][q * 16 + k4 * 4];
            acc += av.x * wl[4 * k4] + av.y * wl[4 * k4 + 1] +
                   av.z * wl[4 * k4 + 2] + av.w * wl[4 * k4 + 3];
            acc += hv.x * wr[4 * k4] + hv.y * wr[4 * k4 + 1] +
                   hv.z * wr[4 * k4 + 2] + hv.w * wr[4 * k4 + 3];
        }
        acc += __shfl_xor(acc, 16);
        acc += __shfl_xor(acc, 32);
        acc += bias;
        float m = acc;
        m = fmaxf(m, __shfl_xor(m, 1));
        m = fmaxf(m, __shfl_xor(m, 2));
        m = fmaxf(m, __shfl_xor(m, 4));
        m = fmaxf(m, __shfl_xor(m, 8));
        float ex = expf(acc - m);
        float s = ex;
        s += __shfl_xor(s, 1);
        s += __shfl_xor(s, 2);
        s += __shfl_xor(s, 4);
        s += __shfl_xor(s, 8);
        if (lane < 16) out[(size_t)n * 16 + lane] = ex / s;
    }
}

extern "C" void kernel_launch(void* const* d_in, const int* in_sizes, int n_in,
                              void* d_out, int out_size, void* d_ws, size_t ws_size,
                              hipStream_t stream) {
    const float* x   = (const float*)d_in[0];
    const int*   ei  = (const int*)d_in[1];
    const float* W2l = (const float*)d_in[2];
    const float* W2r = (const float*)d_in[3];
    const float* b2  = (const float*)d_in[4];
    const float* W3l = (const float*)d_in[5];
    const float* W3r = (const float*)d_in[6];
    const float* b3  = (const float*)d_in[7];
    float* out = (float*)d_out;

    const int* dst = ei;           // edge_index[0]
    const int* src = ei + NEDGES;  // edge_index[1]

    char* ws = (char*)d_ws;
    float*    bufA    = (float*)ws;    ws += (size_t)NNODES * 64 * 4;  // pairtmp -> h1 -> h3
    float*    bufB    = (float*)ws;    ws += (size_t)NNODES * 64 * 4;  // h2
    float*    bufC    = (float*)ws;    ws += (size_t)NNODES * 64 * 4;  // g1b -> agg -> agg2
    unsigned short* bufD = (unsigned short*)ws; ws += (size_t)NNODES * 64 * 2;  // g0b -> h2b -> h3b
    int*      col     = (int*)ws;      ws += (size_t)NEDGES * 4;
    int*      deg     = (int*)ws;      ws += (size_t)NNODES * 4;
    int*      rowoff  = (int*)ws;      ws += (size_t)NNODES * 4;
    float*    dinv    = (float*)ws;    ws += (size_t)NNODES * 4;
    int*      gcur    = (int*)ws;      ws += NBUCK * 4;
    int*      basearr = (int*)ws;      ws += NBUCK * 4;

    unsigned* pairtmp = (unsigned*)bufA;          // 391*4800*4 = 7.5 MB < 25.6 MB, dead before h1
    unsigned short* g1b = (unsigned short*)bufC;  // dead before agg written

    hipMemsetAsync(gcur, 0, NBUCK * 4, stream);

    split_kernel<<<NSPLIT, 256, 0, stream>>>(dst, src, gcur, pairtmp);
    bucketscan_kernel<<<1, 512, 0, stream>>>(gcur, basearr);
    finalize_kernel<<<NBUCK, 256, 0, stream>>>(pairtmp, gcur, basearr, x,
                                               col, deg, rowoff, dinv, bufD);

    int nblk = NNODES / 4;  // 25000, exact
    // KProp step 1: h1 = x + dinv*sum(g0), g1b = bf16(dinv*h1)
    gatherw_kernel<0><<<nblk, 256, 0, stream>>>(bufD, x, bufA, g1b, rowoff, deg, col, dinv);
    // KProp step 2: h2 = h1 + dinv*sum(g1), h2b = bf16(h2)
    gatherw_kernel<1><<<nblk, 256, 0, stream>>>(g1b, bufA, bufB, bufD, rowoff, deg, col, dinv);
    // SAGE1 aggregate: agg = mean(h2b[neigh])
    gatherw_kernel<2><<<nblk, 256, 0, stream>>>(bufD, nullptr, bufC, nullptr, rowoff, deg, col, dinv);
    // dense1: h3 = selu(agg@W2l + h2@W2r + b2), h3b = bf16(h3)
    dense1_kernel<<<2048, 256, 0, stream>>>(bufC, bufB, bufA, bufD, W2l, W2r, b2);
    // SAGE2 aggregate: agg2 = mean(h3b[neigh])
    gatherw_kernel<2><<<nblk, 256, 0, stream>>>(bufD, nullptr, bufC, nullptr, rowoff, deg, col, dinv);
    // dense2 + softmax
    dense2_kernel<<<2048, 256, 0, stream>>>(bufC, bufA, out, W3l, W3r, b3);
}

// Round 5
// 352.946 us; speedup vs baseline: 3.0355x; 1.1689x over previous
//
#include <hip/hip_runtime.h>
#include <hip/hip_bf16.h>

#define NNODES 100000
#define NEDGES 1600000
#define NBUCK 391           // ceil(100000/256) buckets of 256 nodes
#define BCAP 4800           // slack capacity per bucket (mean 4096, sigma ~64)
#define SPLIT_TILE 2048
#define NSPLIT ((NEDGES + SPLIT_TILE - 1) / SPLIT_TILE)  // 782

typedef short short8 __attribute__((ext_vector_type(8)));
typedef float floatx4 __attribute__((ext_vector_type(4)));

__device__ __forceinline__ void f4add(float4& a, const float4& v) {
    a.x += v.x; a.y += v.y; a.z += v.z; a.w += v.w;
}

// bf16 (stored as ushort) -> f32 : exact, one shift
__device__ __forceinline__ float4 b4tof4(ushort4 u) {
    return make_float4(__uint_as_float((unsigned)u.x << 16),
                       __uint_as_float((unsigned)u.y << 16),
                       __uint_as_float((unsigned)u.z << 16),
                       __uint_as_float((unsigned)u.w << 16));
}

// f32 -> bf16 RNE
__device__ __forceinline__ unsigned short f2b(float f) {
    unsigned u = __float_as_uint(f);
    u += 0x7fffu + ((u >> 16) & 1u);
    return (unsigned short)(u >> 16);
}

// ---------------- split: bucket edges by dst>>8 into slack regions ----------------
// packed u32 = (src << 8) | (dst & 255)   (src < 2^17)
__global__ __launch_bounds__(256) void split_kernel(
    const int* __restrict__ dst, const int* __restrict__ src,
    int* __restrict__ gcur, unsigned* __restrict__ pairtmp) {
    __shared__ int lhist[NBUCK];
    __shared__ int lstart[NBUCK];
    __shared__ int ldst[SPLIT_TILE];
    int t = threadIdx.x;
    for (int i = t; i < NBUCK; i += 256) lhist[i] = 0;
    __syncthreads();
    int base = blockIdx.x * SPLIT_TILE;
    int n = min(SPLIT_TILE, NEDGES - base);
    for (int i = t; i < n; i += 256) {
        int d = dst[base + i];
        ldst[i] = d;
        atomicAdd(&lhist[d >> 8], 1);
    }
    __syncthreads();
    for (int i = t; i < NBUCK; i += 256) {
        int c = lhist[i];
        lstart[i] = (c > 0) ? atomicAdd(&gcur[i], c) : 0;
        lhist[i] = 0;  // reuse as local cursor
    }
    __syncthreads();
    for (int i = t; i < n; i += 256) {
        int d = ldst[i];
        int k = d >> 8;
        int s = src[base + i];
        int pos = lstart[k] + atomicAdd(&lhist[k], 1);
        pairtmp[(size_t)k * BCAP + pos] = ((unsigned)s << 8) | (unsigned)(d & 255);
    }
}

// ---------------- exclusive scan of 391 bucket counts ----------------
__global__ void bucketscan_kernel(const int* __restrict__ gcur, int* __restrict__ basearr) {
    __shared__ int lds[512];
    int t = threadIdx.x;
    int v = (t < NBUCK) ? gcur[t] : 0;
    lds[t] = v;
    __syncthreads();
    for (int s = 1; s < 512; s <<= 1) {
        int u = (t >= s) ? lds[t - s] : 0;
        __syncthreads();
        lds[t] += u;
        __syncthreads();
    }
    if (t < NBUCK) basearr[t] = lds[t] - v;
}

// ---------------- finalize: per-bucket CSR build + deg/rowoff/dinv + g0b ----------------
__global__ __launch_bounds__(256) void finalize_kernel(
    const unsigned* __restrict__ pairtmp, const int* __restrict__ gcur,
    const int* __restrict__ basearr, const float* __restrict__ x,
    int* __restrict__ col, int* __restrict__ deg, int* __restrict__ rowoff,
    float* __restrict__ dinv, unsigned short* __restrict__ g0b) {
    __shared__ int ldeg[256];
    __shared__ int lcur[256];
    __shared__ float ldi[256];
    __shared__ int lsc[256];
    int k = blockIdx.x;
    int t = threadIdx.x;
    int node0 = k << 8;
    int ncount = min(256, NNODES - node0);
    int base = basearr[k];
    int count = gcur[k];
    ldeg[t] = 0;
    __syncthreads();
    const unsigned* pb = pairtmp + (size_t)k * BCAP;
    for (int i = t; i < count; i += 256) {
        atomicAdd(&ldeg[pb[i] & 255], 1);
    }
    __syncthreads();
    int a = ldeg[t];
    lsc[t] = a;
    __syncthreads();
    for (int s = 1; s < 256; s <<= 1) {
        int v = (t >= s) ? lsc[t - s] : 0;
        __syncthreads();
        lsc[t] += v;
        __syncthreads();
    }
    int excl = lsc[t] - a;
    lcur[t] = base + excl;
    if (t < ncount) {
        int n0 = node0 + t;
        rowoff[n0] = base + excl;
        deg[n0] = a;
        float di = (a > 0) ? rsqrtf((float)a) : 0.0f;
        ldi[t] = di;
        dinv[n0] = di;
    }
    __syncthreads();
    // scatter col within this bucket's contiguous region (L2-local)
    for (int i = t; i < count; i += 256) {
        unsigned p = pb[i];
        int dl = (int)(p & 255u);
        int s = (int)(p >> 8);
        int pos = atomicAdd(&lcur[dl], 1);
        col[pos] = s;
    }
    // fused g0b = bf16(dinv * x) for this bucket's nodes
    const float4* x4 = (const float4*)x;
    int f4count = ncount * 16;
    int b4 = node0 * 16;
    for (int j = t; j < f4count; j += 256) {
        float di = ldi[j >> 4];
        float4 v = x4[b4 + j];
        ushort4 u;
        u.x = f2b(di * v.x); u.y = f2b(di * v.y);
        u.z = f2b(di * v.z); u.w = f2b(di * v.w);
        *(ushort4*)(g0b + (size_t)(b4 + j) * 4) = u;
    }
}

// ---------------- gather: one node per 64-lane wave, bf16 rows ----------------
// 4 groups x 16 lanes x ushort4(8B); unroll-2 -> 8 rows in flight
// MODE 0: h1 = h + dinv*sum (f32 out) ; g1b = bf16(dinv*h1)
// MODE 1: h2b = bf16(h + dinv*sum)  (bf16 out only)
// MODE 2: aggb = bf16(mean)
template <int MODE>
__global__ __launch_bounds__(256) void gatherw_kernel(
    const unsigned short* __restrict__ vin, const float* __restrict__ hin,
    float* __restrict__ outf, unsigned short* __restrict__ outb,
    const int* __restrict__ rowoff, const int* __restrict__ deg,
    const int* __restrict__ col, const float* __restrict__ dinv) {
    int node = blockIdx.x * 4 + (threadIdx.x >> 6);  // 25000*4 == 100000 exactly
    int lane = threadIdx.x & 63;
    int sub = lane & 15;
    int g = lane >> 4;
    int beg = rowoff[node];
    int dg = deg[node];
    int end = beg + dg;
    float4 a0 = {0.f, 0.f, 0.f, 0.f};
    float4 a1 = {0.f, 0.f, 0.f, 0.f};
    int e = beg + g;
    for (; e + 4 < end; e += 8) {
        int c0 = col[e];
        int c1 = col[e + 4];
        ushort4 u0 = *(const ushort4*)(vin + (size_t)c0 * 64 + sub * 4);
        ushort4 u1 = *(const ushort4*)(vin + (size_t)c1 * 64 + sub * 4);
        f4add(a0, b4tof4(u0));
        f4add(a1, b4tof4(u1));
    }
    if (e < end) {
        int c0 = col[e];
        ushort4 u0 = *(const ushort4*)(vin + (size_t)c0 * 64 + sub * 4);
        f4add(a0, b4tof4(u0));
    }
    f4add(a0, a1);
    a0.x += __shfl_xor(a0.x, 16); a0.y += __shfl_xor(a0.y, 16);
    a0.z += __shfl_xor(a0.z, 16); a0.w += __shfl_xor(a0.w, 16);
    a0.x += __shfl_xor(a0.x, 32); a0.y += __shfl_xor(a0.y, 32);
    a0.z += __shfl_xor(a0.z, 32); a0.w += __shfl_xor(a0.w, 32);
    if (lane < 16) {
        size_t off = (size_t)node * 64 + sub * 4;
        if (MODE <= 1) {
            float di = dinv[node];
            float4 h = *(const float4*)(hin + off);
            float4 hn = make_float4(h.x + di * a0.x, h.y + di * a0.y,
                                    h.z + di * a0.z, h.w + di * a0.w);
            if (MODE == 0) {
                *(float4*)(outf + off) = hn;
                ushort4 u;
                u.x = f2b(di * hn.x); u.y = f2b(di * hn.y);
                u.z = f2b(di * hn.z); u.w = f2b(di * hn.w);
                *(ushort4*)(outb + off) = u;
            } else {
                ushort4 u;
                u.x = f2b(hn.x); u.y = f2b(hn.y);
                u.z = f2b(hn.z); u.w = f2b(hn.w);
                *(ushort4*)(outb + off) = u;
            }
        } else {
            float r = 1.0f / (float)(dg > 0 ? dg : 1);
            ushort4 u;
            u.x = f2b(a0.x * r); u.y = f2b(a0.y * r);
            u.z = f2b(a0.z * r); u.w = f2b(a0.w * r);
            *(ushort4*)(outb + off) = u;
        }
    }
}

// ---------------- dense1 (MFMA): h3 = selu([agg|h2] @ [W2l;W2r] + b2), bf16 out ----------------
// One 16-node tile per wave. A: bf16 rows (lane&15 = node, k contiguous).
// B: Wt[j][k] bf16 in LDS (padded stride 144). C: col=lane&15 (=j), row=(lane>>4)*4+reg.
__global__ __launch_bounds__(256) void dense1_mfma(
    const unsigned short* __restrict__ aggb, const unsigned short* __restrict__ hb,
    unsigned short* __restrict__ h3b,
    const float* __restrict__ W2l, const float* __restrict__ W2r,
    const float* __restrict__ b2) {
    __shared__ unsigned short Wt[64 * 144];
    int t = threadIdx.x;
    for (int idx = t; idx < 128 * 64; idx += 256) {
        int k = idx >> 6, j = idx & 63;
        float v = (k < 64) ? W2l[k * 64 + j] : W2r[(k - 64) * 64 + j];
        Wt[j * 144 + k] = f2b(v);
    }
    __syncthreads();
    int wib = t >> 6, lane = t & 63;
    int tile = blockIdx.x * 4 + wib;
    if (tile * 16 >= NNODES) return;
    int node0 = tile * 16;
    int jj = lane & 15, kg = lane >> 4;
    short8 bfrag[4][4];
#pragma unroll
    for (int nt = 0; nt < 4; ++nt)
#pragma unroll
        for (int s = 0; s < 4; ++s)
            bfrag[nt][s] = *(const short8*)&Wt[(nt * 16 + jj) * 144 + s * 32 + kg * 8];
    int arow = node0 + jj;
    const unsigned short* ap = aggb + (size_t)arow * 64 + kg * 8;
    const unsigned short* hp = hb + (size_t)arow * 64 + kg * 8;
    short8 afrag[4];
    afrag[0] = *(const short8*)ap;
    afrag[1] = *(const short8*)(ap + 32);
    afrag[2] = *(const short8*)hp;
    afrag[3] = *(const short8*)(hp + 32);
    const float lam = 1.0507009873554804934193349852946f;
    const float alp = 1.6732632423543772848170429916717f;
#pragma unroll
    for (int nt = 0; nt < 4; ++nt) {
        floatx4 acc = {0.f, 0.f, 0.f, 0.f};
#pragma unroll
        for (int s = 0; s < 4; ++s)
            acc = __builtin_amdgcn_mfma_f32_16x16x32_bf16(afrag[s], bfrag[nt][s], acc, 0, 0, 0);
        float bias = b2[nt * 16 + jj];
#pragma unroll
        for (int r = 0; r < 4; ++r) {
            float v = acc[r] + bias;
            float o = (v > 0.0f) ? lam * v : lam * alp * expm1f(v);
            int node = node0 + kg * 4 + r;
            h3b[(size_t)node * 64 + nt * 16 + jj] = f2b(o);
        }
    }
}

// ---------------- dense2 (MFMA) + softmax(16) ----------------
__global__ __launch_bounds__(256) void dense2_mfma(
    const unsigned short* __restrict__ aggb, const unsigned short* __restrict__ hb,
    float* __restrict__ out,
    const float* __restrict__ W3l, const float* __restrict__ W3r,
    const float* __restrict__ b3) {
    __shared__ unsigned short Wt[16 * 144];
    int t = threadIdx.x;
    for (int idx = t; idx < 128 * 16; idx += 256) {
        int k = idx >> 4, j = idx & 15;
        float v = (k < 64) ? W3l[k * 16 + j] : W3r[(k - 64) * 16 + j];
        Wt[j * 144 + k] = f2b(v);
    }
    __syncthreads();
    int wib = t >> 6, lane = t & 63;
    int tile = blockIdx.x * 4 + wib;
    if (tile * 16 >= NNODES) return;
    int node0 = tile * 16;
    int jj = lane & 15, kg = lane >> 4;
    short8 bfrag[4];
#pragma unroll
    for (int s = 0; s < 4; ++s)
        bfrag[s] = *(const short8*)&Wt[jj * 144 + s * 32 + kg * 8];
    int arow = node0 + jj;
    const unsigned short* ap = aggb + (size_t)arow * 64 + kg * 8;
    const unsigned short* hp = hb + (size_t)arow * 64 + kg * 8;
    short8 afrag[4];
    afrag[0] = *(const short8*)ap;
    afrag[1] = *(const short8*)(ap + 32);
    afrag[2] = *(const short8*)hp;
    afrag[3] = *(const short8*)(hp + 32);
    floatx4 acc = {0.f, 0.f, 0.f, 0.f};
#pragma unroll
    for (int s = 0; s < 4; ++s)
        acc = __builtin_amdgcn_mfma_f32_16x16x32_bf16(afrag[s], bfrag[s], acc, 0, 0, 0);
    float bias = b3[jj];
#pragma unroll
    for (int r = 0; r < 4; ++r) {
        float v = acc[r] + bias;
        float m = v;
        m = fmaxf(m, __shfl_xor(m, 1));
        m = fmaxf(m, __shfl_xor(m, 2));
        m = fmaxf(m, __shfl_xor(m, 4));
        m = fmaxf(m, __shfl_xor(m, 8));
        float ex = expf(v - m);
        float s2 = ex;
        s2 += __shfl_xor(s2, 1);
        s2 += __shfl_xor(s2, 2);
        s2 += __shfl_xor(s2, 4);
        s2 += __shfl_xor(s2, 8);
        int node = node0 + kg * 4 + r;
        out[(size_t)node * 16 + jj] = ex / s2;
    }
}

extern "C" void kernel_launch(void* const* d_in, const int* in_sizes, int n_in,
                              void* d_out, int out_size, void* d_ws, size_t ws_size,
                              hipStream_t stream) {
    const float* x   = (const float*)d_in[0];
    const int*   ei  = (const int*)d_in[1];
    const float* W2l = (const float*)d_in[2];
    const float* W2r = (const float*)d_in[3];
    const float* b2  = (const float*)d_in[4];
    const float* W3l = (const float*)d_in[5];
    const float* W3r = (const float*)d_in[6];
    const float* b3  = (const float*)d_in[7];
    float* out = (float*)d_out;

    const int* dst = ei;           // edge_index[0]
    const int* src = ei + NEDGES;  // edge_index[1]

    char* ws = (char*)d_ws;
    float*          bufA = (float*)ws;          ws += (size_t)NNODES * 64 * 4;  // pairtmp -> h1 -> h3b
    unsigned short* E0   = (unsigned short*)ws; ws += (size_t)NNODES * 64 * 2;  // g0b -> h2b -> agg2b
    unsigned short* E1   = (unsigned short*)ws; ws += (size_t)NNODES * 64 * 2;  // g1b -> agg1b
    int*      col     = (int*)ws;      ws += (size_t)NEDGES * 4;
    int*      deg     = (int*)ws;      ws += (size_t)NNODES * 4;
    int*      rowoff  = (int*)ws;      ws += (size_t)NNODES * 4;
    float*    dinv    = (float*)ws;    ws += (size_t)NNODES * 4;
    int*      gcur    = (int*)ws;      ws += NBUCK * 4;
    int*      basearr = (int*)ws;      ws += NBUCK * 4;

    unsigned* pairtmp = (unsigned*)bufA;          // 7.5 MB, dead before h1 written
    unsigned short* h3b = (unsigned short*)bufA;  // h1 dead before h3b written

    hipMemsetAsync(gcur, 0, NBUCK * 4, stream);

    split_kernel<<<NSPLIT, 256, 0, stream>>>(dst, src, gcur, pairtmp);
    bucketscan_kernel<<<1, 512, 0, stream>>>(gcur, basearr);
    finalize_kernel<<<NBUCK, 256, 0, stream>>>(pairtmp, gcur, basearr, x,
                                               col, deg, rowoff, dinv, E0);

    int nblk = NNODES / 4;       // 25000, exact
    int ndense = (NNODES / 16 + 3) / 4;  // 1563 blocks, 4 tiles each
    // KProp step 1: h1 = x + dinv*sum(g0), g1b = bf16(dinv*h1)
    gatherw_kernel<0><<<nblk, 256, 0, stream>>>(E0, x, bufA, E1, rowoff, deg, col, dinv);
    // KProp step 2: h2b = bf16(h1 + dinv*sum(g1))
    gatherw_kernel<1><<<nblk, 256, 0, stream>>>(E1, bufA, nullptr, E0, rowoff, deg, col, dinv);
    // SAGE1 aggregate: agg1b = bf16(mean(h2b[neigh]))
    gatherw_kernel<2><<<nblk, 256, 0, stream>>>(E0, nullptr, nullptr, E1, rowoff, deg, col, dinv);
    // dense1: h3b = bf16(selu(agg1@W2l + h2@W2r + b2))
    dense1_mfma<<<ndense, 256, 0, stream>>>(E1, E0, h3b, W2l, W2r, b2);
    // SAGE2 aggregate: agg2b = bf16(mean(h3b[neigh]))
    gatherw_kernel<2><<<nblk, 256, 0, stream>>>(h3b, nullptr, nullptr, E0, rowoff, deg, col, dinv);
    // dense2 + softmax
    dense2_mfma<<<ndense, 256, 0, stream>>>(E0, h3b, out, W3l, W3r, b3);
}

// Round 6
// 327.716 us; speedup vs baseline: 3.2692x; 1.0770x over previous
//
#include <hip/hip_runtime.h>
#include <hip/hip_bf16.h>

#define NNODES 100000
#define NEDGES 1600000
#define NC 25               // coarse buckets of 4096 nodes (dst>>12)
#define CAP1 68000          // coarse slack (mean 65536, +~10 sigma)
#define NBUCK 391           // fine buckets of 256 nodes
#define BCAP 4800           // fine slack (mean 4096, +11 sigma)
#define SPLIT_TILE 2048
#define NSPLIT ((NEDGES + SPLIT_TILE - 1) / SPLIT_TILE)  // 782
#define T2TILES 17          // ceil(CAP1 / 4096)

typedef short short8 __attribute__((ext_vector_type(8)));
typedef unsigned short ushx8 __attribute__((ext_vector_type(8)));
typedef float floatx4 __attribute__((ext_vector_type(4)));

// f32 -> bf16 RNE
__device__ __forceinline__ unsigned short f2b(float f) {
    unsigned u = __float_as_uint(f);
    u += 0x7fffu + ((u >> 16) & 1u);
    return (unsigned short)(u >> 16);
}

__device__ __forceinline__ void acc8(float* a, ushx8 u) {
#pragma unroll
    for (int i = 0; i < 8; ++i)
        a[i] += __uint_as_float((unsigned)u[i] << 16);
}

// ---------------- split pass 1: 25 coarse buckets by dst>>12 ----------------
// packed u32 = (src << 12) | (dst & 4095)   (src < 2^17)
__global__ __launch_bounds__(256) void split1_kernel(
    const int* __restrict__ dst, const int* __restrict__ src,
    int* __restrict__ gcur1, unsigned* __restrict__ cpairs) {
    __shared__ int lhist[NC];
    __shared__ int lstart[NC];
    __shared__ int ldst[SPLIT_TILE];
    int t = threadIdx.x;
    if (t < NC) lhist[t] = 0;
    __syncthreads();
    int base = blockIdx.x * SPLIT_TILE;
    int n = min(SPLIT_TILE, NEDGES - base);
    for (int i = t; i < n; i += 256) {
        int d = dst[base + i];
        ldst[i] = d;
        atomicAdd(&lhist[d >> 12], 1);
    }
    __syncthreads();
    if (t < NC) {
        int c = lhist[t];
        lstart[t] = (c > 0) ? atomicAdd(&gcur1[t], c) : 0;
        lhist[t] = 0;  // reuse as local cursor
    }
    __syncthreads();
    for (int i = t; i < n; i += 256) {
        int d = ldst[i];
        int k = d >> 12;
        int s = src[base + i];
        int pos = lstart[k] + atomicAdd(&lhist[k], 1);
        cpairs[(size_t)k * CAP1 + pos] = ((unsigned)s << 12) | (unsigned)(d & 4095);
    }
}

// ---------------- split pass 2: coarse -> 16 fine buckets each ----------------
// repack to (src << 8) | (dst & 255)
__global__ __launch_bounds__(256) void split2_kernel(
    const unsigned* __restrict__ cpairs, const int* __restrict__ gcur1,
    int* __restrict__ gcur2, unsigned* __restrict__ fpairs) {
    int c = blockIdx.x / T2TILES;
    int tile = blockIdx.x % T2TILES;
    int cnt = gcur1[c];
    int base = tile * 4096;
    if (base >= cnt) return;
    int n = min(4096, cnt - base);
    __shared__ unsigned stash[4096];
    __shared__ int lhist[16];
    __shared__ int lstart[16];
    int t = threadIdx.x;
    if (t < 16) lhist[t] = 0;
    __syncthreads();
    const unsigned* pb = cpairs + (size_t)c * CAP1 + base;
    for (int i = t; i < n; i += 256) {
        unsigned p = pb[i];
        stash[i] = p;
        atomicAdd(&lhist[(p >> 8) & 15], 1);
    }
    __syncthreads();
    if (t < 16) {
        int cc = lhist[t];
        lstart[t] = (cc > 0) ? atomicAdd(&gcur2[c * 16 + t], cc) : 0;
        lhist[t] = 0;
    }
    __syncthreads();
    for (int i = t; i < n; i += 256) {
        unsigned p = stash[i];
        int f = (p >> 8) & 15;
        int pos = lstart[f] + atomicAdd(&lhist[f], 1);
        fpairs[(size_t)(c * 16 + f) * BCAP + pos] = ((p >> 12) << 8) | (p & 255u);
    }
}

// ---------------- exclusive scan of 391 fine-bucket counts ----------------
__global__ void bucketscan_kernel(const int* __restrict__ gcur2, int* __restrict__ basearr) {
    __shared__ int lds[512];
    int t = threadIdx.x;
    int v = (t < NBUCK) ? gcur2[t] : 0;
    lds[t] = v;
    __syncthreads();
    for (int s = 1; s < 512; s <<= 1) {
        int u = (t >= s) ? lds[t - s] : 0;
        __syncthreads();
        lds[t] += u;
        __syncthreads();
    }
    if (t < NBUCK) basearr[t] = lds[t] - v;
}

// ---------------- finalize: per-bucket CSR build + deg/rowoff/dinv + g0b ----------------
__global__ __launch_bounds__(256) void finalize_kernel(
    const unsigned* __restrict__ fpairs, const int* __restrict__ gcur2,
    const int* __restrict__ basearr, const float* __restrict__ x,
    int* __restrict__ col, int* __restrict__ deg, int* __restrict__ rowoff,
    float* __restrict__ dinv, unsigned short* __restrict__ g0b) {
    __shared__ int ldeg[256];
    __shared__ int lcur[256];
    __shared__ float ldi[256];
    __shared__ int lsc[256];
    int k = blockIdx.x;
    int t = threadIdx.x;
    int node0 = k << 8;
    int ncount = min(256, NNODES - node0);
    int base = basearr[k];
    int count = gcur2[k];
    ldeg[t] = 0;
    __syncthreads();
    const unsigned* pb = fpairs + (size_t)k * BCAP;
    for (int i = t; i < count; i += 256) {
        atomicAdd(&ldeg[pb[i] & 255], 1);
    }
    __syncthreads();
    int a = ldeg[t];
    lsc[t] = a;
    __syncthreads();
    for (int s = 1; s < 256; s <<= 1) {
        int v = (t >= s) ? lsc[t - s] : 0;
        __syncthreads();
        lsc[t] += v;
        __syncthreads();
    }
    int excl = lsc[t] - a;
    lcur[t] = base + excl;
    if (t < ncount) {
        int n0 = node0 + t;
        rowoff[n0] = base + excl;
        deg[n0] = a;
        float di = (a > 0) ? rsqrtf((float)a) : 0.0f;
        ldi[t] = di;
        dinv[n0] = di;
    }
    __syncthreads();
    for (int i = t; i < count; i += 256) {
        unsigned p = pb[i];
        int dl = (int)(p & 255u);
        int s = (int)(p >> 8);
        int pos = atomicAdd(&lcur[dl], 1);
        col[pos] = s;
    }
    // fused g0b = bf16(dinv * x)
    const float4* x4 = (const float4*)x;
    int f4count = ncount * 16;
    int b4 = node0 * 16;
    for (int j = t; j < f4count; j += 256) {
        float di = ldi[j >> 4];
        float4 v = x4[b4 + j];
        ushort4 u;
        u.x = f2b(di * v.x); u.y = f2b(di * v.y);
        u.z = f2b(di * v.z); u.w = f2b(di * v.w);
        *(ushort4*)(g0b + (size_t)(b4 + j) * 4) = u;
    }
}

// ---------------- gather: one node per wave, 8 groups x 8 lanes x 16B ----------------
// unroll-2 -> 16 rows in flight per wave
// MODE 0: h1b = bf16(x + dinv*sum), g1b = bf16(dinv*h1)   (residual = f32 x)
// MODE 1: h2b = bf16(h1b + dinv*sum)                       (residual = bf16)
// MODE 2: aggb = bf16(sum/degm)
template <int MODE>
__global__ __launch_bounds__(256) void gatherw_kernel(
    const unsigned short* __restrict__ vin, const float* __restrict__ hinf,
    const unsigned short* __restrict__ hinb,
    unsigned short* __restrict__ out0, unsigned short* __restrict__ out1,
    const int* __restrict__ rowoff, const int* __restrict__ deg,
    const int* __restrict__ col, const float* __restrict__ dinv) {
    int node = blockIdx.x * 4 + (threadIdx.x >> 6);  // 25000*4 == 100000 exactly
    int lane = threadIdx.x & 63;
    int sub = lane & 7;
    int g = lane >> 3;
    int beg = rowoff[node];
    int dg = deg[node];
    int end = beg + dg;
    float af[8] = {0.f, 0.f, 0.f, 0.f, 0.f, 0.f, 0.f, 0.f};
    float bf[8] = {0.f, 0.f, 0.f, 0.f, 0.f, 0.f, 0.f, 0.f};
    int e = beg + g;
    for (; e + 8 < end; e += 16) {
        int c0 = col[e];
        int c1 = col[e + 8];
        ushx8 u0 = *(const ushx8*)(vin + (size_t)c0 * 64 + sub * 8);
        ushx8 u1 = *(const ushx8*)(vin + (size_t)c1 * 64 + sub * 8);
        acc8(af, u0);
        acc8(bf, u1);
    }
    if (e < end) {
        int c0 = col[e];
        ushx8 u0 = *(const ushx8*)(vin + (size_t)c0 * 64 + sub * 8);
        acc8(af, u0);
    }
#pragma unroll
    for (int i = 0; i < 8; ++i) {
        float v = af[i] + bf[i];
        v += __shfl_xor(v, 8);
        v += __shfl_xor(v, 16);
        v += __shfl_xor(v, 32);
        af[i] = v;
    }
    if (lane < 8) {
        size_t off = (size_t)node * 64 + lane * 8;
        if (MODE <= 1) {
            float di = dinv[node];
            float hv[8];
            if (MODE == 0) {
                float4 h0 = *(const float4*)(hinf + off);
                float4 h1 = *(const float4*)(hinf + off + 4);
                hv[0] = h0.x; hv[1] = h0.y; hv[2] = h0.z; hv[3] = h0.w;
                hv[4] = h1.x; hv[5] = h1.y; hv[6] = h1.z; hv[7] = h1.w;
            } else {
                ushx8 u = *(const ushx8*)(hinb + off);
#pragma unroll
                for (int i = 0; i < 8; ++i) hv[i] = __uint_as_float((unsigned)u[i] << 16);
            }
            ushx8 uh, ug;
#pragma unroll
            for (int i = 0; i < 8; ++i) {
                float hn = hv[i] + di * af[i];
                uh[i] = f2b(hn);
                if (MODE == 0) ug[i] = f2b(di * hn);
            }
            *(ushx8*)(out0 + off) = uh;
            if (MODE == 0) *(ushx8*)(out1 + off) = ug;
        } else {
            float r = 1.0f / (float)(dg > 0 ? dg : 1);
            ushx8 u;
#pragma unroll
            for (int i = 0; i < 8; ++i) u[i] = f2b(af[i] * r);
            *(ushx8*)(out0 + off) = u;
        }
    }
}

// ---------------- dense1 (MFMA): h3 = selu([agg|h2] @ [W2l;W2r] + b2), bf16 out ----------------
__global__ __launch_bounds__(256) void dense1_mfma(
    const unsigned short* __restrict__ aggb, const unsigned short* __restrict__ hb,
    unsigned short* __restrict__ h3b,
    const float* __restrict__ W2l, const float* __restrict__ W2r,
    const float* __restrict__ b2) {
    __shared__ unsigned short Wt[64 * 144];
    int t = threadIdx.x;
    for (int idx = t; idx < 128 * 64; idx += 256) {
        int k = idx >> 6, j = idx & 63;
        float v = (k < 64) ? W2l[k * 64 + j] : W2r[(k - 64) * 64 + j];
        Wt[j * 144 + k] = f2b(v);
    }
    __syncthreads();
    int wib = t >> 6, lane = t & 63;
    int tile = blockIdx.x * 4 + wib;
    if (tile * 16 >= NNODES) return;
    int node0 = tile * 16;
    int jj = lane & 15, kg = lane >> 4;
    short8 bfrag[4][4];
#pragma unroll
    for (int nt = 0; nt < 4; ++nt)
#pragma unroll
        for (int s = 0; s < 4; ++s)
            bfrag[nt][s] = *(const short8*)&Wt[(nt * 16 + jj) * 144 + s * 32 + kg * 8];
    int arow = node0 + jj;
    const unsigned short* ap = aggb + (size_t)arow * 64 + kg * 8;
    const unsigned short* hp = hb + (size_t)arow * 64 + kg * 8;
    short8 afrag[4];
    afrag[0] = *(const short8*)ap;
    afrag[1] = *(const short8*)(ap + 32);
    afrag[2] = *(const short8*)hp;
    afrag[3] = *(const short8*)(hp + 32);
    const float lam = 1.0507009873554804934193349852946f;
    const float alp = 1.6732632423543772848170429916717f;
#pragma unroll
    for (int nt = 0; nt < 4; ++nt) {
        floatx4 acc = {0.f, 0.f, 0.f, 0.f};
#pragma unroll
        for (int s = 0; s < 4; ++s)
            acc = __builtin_amdgcn_mfma_f32_16x16x32_bf16(afrag[s], bfrag[nt][s], acc, 0, 0, 0);
        float bias = b2[nt * 16 + jj];
#pragma unroll
        for (int r = 0; r < 4; ++r) {
            float v = acc[r] + bias;
            float o = (v > 0.0f) ? lam * v : lam * alp * expm1f(v);
            int node = node0 + kg * 4 + r;
            h3b[(size_t)node * 64 + nt * 16 + jj] = f2b(o);
        }
    }
}

// ---------------- dense2 (MFMA) + softmax(16) ----------------
__global__ __launch_bounds__(256) void dense2_mfma(
    const unsigned short* __restrict__ aggb, const unsigned short* __restrict__ hb,
    float* __restrict__ out,
    const float* __restrict__ W3l, const float* __restrict__ W3r,
    const float* __restrict__ b3) {
    __shared__ unsigned short Wt[16 * 144];
    int t = threadIdx.x;
    for (int idx = t; idx < 128 * 16; idx += 256) {
        int k = idx >> 4, j = idx & 15;
        float v = (k < 64) ? W3l[k * 16 + j] : W3r[(k - 64) * 16 + j];
        Wt[j * 144 + k] = f2b(v);
    }
    __syncthreads();
    int wib = t >> 6, lane = t & 63;
    int tile = blockIdx.x * 4 + wib;
    if (tile * 16 >= NNODES) return;
    int node0 = tile * 16;
    int jj = lane & 15, kg = lane >> 4;
    short8 bfrag[4];
#pragma unroll
    for (int s = 0; s < 4; ++s)
        bfrag[s] = *(const short8*)&Wt[jj * 144 + s * 32 + kg * 8];
    int arow = node0 + jj;
    const unsigned short* ap = aggb + (size_t)arow * 64 + kg * 8;
    const unsigned short* hp = hb + (size_t)arow * 64 + kg * 8;
    short8 afrag[4];
    afrag[0] = *(const short8*)ap;
    afrag[1] = *(const short8*)(ap + 32);
    afrag[2] = *(const short8*)hp;
    afrag[3] = *(const short8*)(hp + 32);
    floatx4 acc = {0.f, 0.f, 0.f, 0.f};
#pragma unroll
    for (int s = 0; s < 4; ++s)
        acc = __builtin_amdgcn_mfma_f32_16x16x32_bf16(afrag[s], bfrag[s], acc, 0, 0, 0);
    float bias = b3[jj];
#pragma unroll
    for (int r = 0; r < 4; ++r) {
        float v = acc[r] + bias;
        float m = v;
        m = fmaxf(m, __shfl_xor(m, 1));
        m = fmaxf(m, __shfl_xor(m, 2));
        m = fmaxf(m, __shfl_xor(m, 4));
        m = fmaxf(m, __shfl_xor(m, 8));
        float ex = expf(v - m);
        float s2 = ex;
        s2 += __shfl_xor(s2, 1);
        s2 += __shfl_xor(s2, 2);
        s2 += __shfl_xor(s2, 4);
        s2 += __shfl_xor(s2, 8);
        int node = node0 + kg * 4 + r;
        out[(size_t)node * 16 + jj] = ex / s2;
    }
}

extern "C" void kernel_launch(void* const* d_in, const int* in_sizes, int n_in,
                              void* d_out, int out_size, void* d_ws, size_t ws_size,
                              hipStream_t stream) {
    const float* x   = (const float*)d_in[0];
    const int*   ei  = (const int*)d_in[1];
    const float* W2l = (const float*)d_in[2];
    const float* W2r = (const float*)d_in[3];
    const float* b2  = (const float*)d_in[4];
    const float* W3l = (const float*)d_in[5];
    const float* W3r = (const float*)d_in[6];
    const float* b3  = (const float*)d_in[7];
    float* out = (float*)d_out;

    const int* dst = ei;           // edge_index[0]
    const int* src = ei + NEDGES;  // edge_index[1]

    char* ws = (char*)d_ws;
    unsigned short* B0 = (unsigned short*)ws; ws += (size_t)NNODES * 64 * 2;  // g0b -> h2b -> agg2b
    unsigned short* B1 = (unsigned short*)ws; ws += (size_t)NNODES * 64 * 2;  // h1b -> agg1b
    unsigned short* B2 = (unsigned short*)ws; ws += (size_t)NNODES * 64 * 2;  // g1b -> h3b
    int*      col     = (int*)ws;      ws += (size_t)NEDGES * 4;
    int*      deg     = (int*)ws;      ws += (size_t)NNODES * 4;
    int*      rowoff  = (int*)ws;      ws += (size_t)NNODES * 4;
    float*    dinv    = (float*)ws;    ws += (size_t)NNODES * 4;
    int*      gcur1   = (int*)ws;      ws += NC * 4;
    int*      gcur2   = (int*)ws;      ws += NBUCK * 4;
    int*      basearr = (int*)ws;      ws += NBUCK * 4;

    // overlays (dead before their hosts are written):
    unsigned* cpairs = (unsigned*)B1;  // 25*68000*4 = 6.8 MB < 12.8 MB; dead after split2
    unsigned* fpairs = (unsigned*)B2;  // 391*4800*4 = 7.5 MB < 12.8 MB; dead after finalize

    hipMemsetAsync(gcur1, 0, (NC + NBUCK) * 4, stream);  // gcur1 + gcur2 adjacent

    split1_kernel<<<NSPLIT, 256, 0, stream>>>(dst, src, gcur1, cpairs);
    split2_kernel<<<NC * T2TILES, 256, 0, stream>>>(cpairs, gcur1, gcur2, fpairs);
    bucketscan_kernel<<<1, 512, 0, stream>>>(gcur2, basearr);
    finalize_kernel<<<NBUCK, 256, 0, stream>>>(fpairs, gcur2, basearr, x,
                                               col, deg, rowoff, dinv, B0);

    int nblk = NNODES / 4;               // 25000, exact
    int ndense = (NNODES / 16 + 3) / 4;  // 1563
    // KProp step 1: h1b = bf16(x + dinv*sum(g0)), g1b = bf16(dinv*h1)
    gatherw_kernel<0><<<nblk, 256, 0, stream>>>(B0, x, nullptr, B1, B2, rowoff, deg, col, dinv);
    // KProp step 2: h2b = bf16(h1b + dinv*sum(g1))
    gatherw_kernel<1><<<nblk, 256, 0, stream>>>(B2, nullptr, B1, B0, nullptr, rowoff, deg, col, dinv);
    // SAGE1 aggregate: agg1b = bf16(mean(h2b[neigh]))
    gatherw_kernel<2><<<nblk, 256, 0, stream>>>(B0, nullptr, nullptr, B1, nullptr, rowoff, deg, col, dinv);
    // dense1: h3b = bf16(selu(agg1@W2l + h2@W2r + b2))
    dense1_mfma<<<ndense, 256, 0, stream>>>(B1, B0, B2, W2l, W2r, b2);
    // SAGE2 aggregate: agg2b = bf16(mean(h3b[neigh]))
    gatherw_kernel<2><<<nblk, 256, 0, stream>>>(B2, nullptr, nullptr, B0, nullptr, rowoff, deg, col, dinv);
    // dense2 + softmax
    dense2_mfma<<<ndense, 256, 0, stream>>>(B0, B2, out, W3l, W3r, b3);
}